// Round 4
// baseline (16920.750 us; speedup 1.0000x reference)
//
#include <hip/hip_runtime.h>
#include <math.h>

#define BATCH 512
#define SEQ_T 128
#define NIN   500
#define HID   1024
#define G3    3072   // 3*HID

typedef float f32x4 __attribute__((ext_vector_type(4)));
typedef _Float16 half8 __attribute__((ext_vector_type(8)));

// ---------------------------------------------------------------------------
// fp32 -> fp16 pair split: v ~= h + l/4096, |err| <= ~2^-23 |v|.
// ---------------------------------------------------------------------------
__device__ __forceinline__ void split_h2(float v, unsigned short &h, unsigned short &l) {
    _Float16 hh = (_Float16)v;
    float hf = (float)hh;
    if (fabsf(hf) < 6.103515625e-5f) { hh = (_Float16)0.f; hf = 0.f; }
    _Float16 ll = (_Float16)((v - hf) * 4096.f);
    h = __builtin_bit_cast(unsigned short, hh);
    l = __builtin_bit_cast(unsigned short, ll);
}

__device__ __forceinline__ float h2f(unsigned short u) {
    return (float)__builtin_bit_cast(_Float16, u);
}

__device__ __forceinline__ void g2lds16(const void* g, void* l) {
    __builtin_amdgcn_global_load_lds(
        (const __attribute__((address_space(1))) void*)g,
        (__attribute__((address_space(3))) void*)l,
        16, 0, 0);
}

// ---------------------------------------------------------------------------
// Lightweight grid barrier: monotonic counter, tid0 release-add + spin +
// acquire-load (wbl2 on release, buffer_inv on acquire -> cross-XCD h
// visibility). Targets are monotonic across launches via tbase (no reset).
// ---------------------------------------------------------------------------
__device__ __forceinline__ void grid_barrier(unsigned* cnt, unsigned target) {
    __syncthreads();                      // per-wave stores drained before release
    if (threadIdx.x == 0) {
        __hip_atomic_fetch_add(cnt, 1u, __ATOMIC_RELEASE, __HIP_MEMORY_SCOPE_AGENT);
        while (__hip_atomic_load(cnt, __ATOMIC_RELAXED, __HIP_MEMORY_SCOPE_AGENT) < target)
            __builtin_amdgcn_s_sleep(2);
        (void)__hip_atomic_load(cnt, __ATOMIC_ACQUIRE, __HIP_MEMORY_SCOPE_AGENT);
    }
    __syncthreads();
    asm volatile("" ::: "memory");        // no load hoisting above the barrier
}

// ---------------------------------------------------------------------------
// Persistent fused GRU layer kernel.
// grid = 256 blocks (8 m-tiles x 32 h-tiles), 512 thr (8 waves), 1 block/CU
// (LDS = 160 KiB exactly). Per step: gh = h_prev @ w_hh^T for this block's
// 32 h-cols x 3 gates (n=96), fp16-pair MFMA; epilogue = GRU gate math +
// h_new plane emission. K-loop: depth-3 staging pipeline over 4 LDS buffers
// with counted-vmcnt asm barriers (never vmcnt(0) mid-loop). Steps separated
// by custom grid_barrier with monotonic targets (tbase + 256*k).
// mode 0: slot sequence [layer 0]; mode 1: ping-pong [layer 1].
// ---------------------------------------------------------------------------
__global__ __launch_bounds__(512, 1) void gru_fused(
    unsigned short* __restrict__ pH, unsigned short* __restrict__ pL,
    int nslots, int mode, int tt0, int nsteps,
    const unsigned short* __restrict__ Wh, const unsigned short* __restrict__ Wl,
    const float* __restrict__ bhh,
    const float* __restrict__ gx,
    unsigned* bar, unsigned tbase)
{
    // slab layout per buffer (16B slots): [0,512) Ah [oct][row64]; [512,1024)
    // Al; [1024,1792) Wh [oct][row96]; [1792,2560) Wl. 40960 B x 4 = 160 KiB.
    // The reduce scratch (64x96 f32 = 24 KiB) aliases buffer 0 post-k-loop.
    __shared__ __align__(16) unsigned short lds[4][2560 * 8];

    const int tid  = threadIdx.x;
    const int lane = tid & 63;
    const int wave = tid >> 6;
    const int ms = wave >> 2, ns = (wave >> 1) & 1, wk = wave & 1;
    const int q = lane >> 4, l16 = lane & 15;
    const int mt = blockIdx.x >> 5, ht = blockIdx.x & 31;  // same-ht blocks share XCD (bid%8 const)
    const int bm = mt << 6, hbase = ht << 5;

    // W staging sources (3 chunks/thread, constant across slabs/steps)
    const unsigned short* wsrc[3];
    #pragma unroll
    for (int i = 0; i < 3; i++) {
        int u = tid + 512 * i;                 // 0..1535
        int pl = u / 768; int rem = u - pl * 768;
        int oct = rem / 96; int r96 = rem - oct * 96;
        int g = r96 >> 5, wr = r96 & 31;
        wsrc[i] = (pl ? Wl : Wh) + (long)((g << 10) + hbase + wr) * 1024 + oct * 8;
    }

    // epilogue constants: thread -> (row, 4 h-cols)
    const int erow = tid >> 3;
    const int ecg  = (tid & 7) << 2;
    const float4 br4 = *(const float4*)&bhh[hbase + ecg];
    const float4 bz4 = *(const float4*)&bhh[1024 + hbase + ecg];
    const float4 bn4 = *(const float4*)&bhh[2048 + hbase + ecg];
    const float ks = 1.0f / 4096.0f;
    const int grow = bm + erow;
    const long po = (long)grow * 1024 + hbase + ecg;

    for (int ttl = 0; ttl < nsteps; ttl++) {
        const int step = tt0 + ttl;
        const int rs    = (mode == 0) ? ((step + nslots - 1) % nslots) : (step & 1);
        const int wslot = (mode == 0) ? (step % nslots) : ((step & 1) ^ 1);
        const unsigned short* srcH = pH + (size_t)rs * 524288;
        const unsigned short* srcL = pL + (size_t)rs * 524288;
        unsigned short* dstH = pH + (size_t)wslot * 524288;
        unsigned short* dstL = pL + (size_t)wslot * 524288;
        const float* gxt = gx + (size_t)ttl * (512 * 3072);

        const unsigned short* aH = srcH + (long)(bm + lane) * 1024 + wave * 8;
        const unsigned short* aL = srcL + (long)(bm + lane) * 1024 + wave * 8;

        // ---- epilogue prefetch: issued first (oldest vmem; drains at s=0) ----
        const float* gp = gxt + (long)grow * 3072 + hbase + ecg;
        float4 xr = *(const float4*)gp;
        float4 xz = *(const float4*)(gp + 1024);
        float4 xn = *(const float4*)(gp + 2048);
        ushort4 hh4 = *(const ushort4*)&srcH[po];
        ushort4 hl4 = *(const ushort4*)&srcL[po];

        auto stage = [&](int b, int s) {
            const long ko = (long)s * 64;
            g2lds16(aH + ko,      &lds[b][(0 * 512 + wave * 64) * 8]);
            g2lds16(aL + ko,      &lds[b][(1 * 512 + wave * 64) * 8]);
            g2lds16(wsrc[0] + ko, &lds[b][(2 * 512 + wave * 64) * 8]);
            g2lds16(wsrc[1] + ko, &lds[b][(3 * 512 + wave * 64) * 8]);
            g2lds16(wsrc[2] + ko, &lds[b][(4 * 512 + wave * 64) * 8]);
        };

        f32x4 acc1[6] = {};
        f32x4 acc2[6] = {};
        stage(0, 0);
        stage(1, 1);
        stage(2, 2);
        #pragma unroll
        for (int s = 0; s < 16; s++) {
            // Complete slab s's 5 staging loads (per wave); keep the 10 loads
            // of slabs s+1,s+2 in flight. lgkmcnt(0): prior ds_reads landed
            // -> safe for post-barrier DMA to overwrite buffer (s+3)&3.
            if (s <= 13)
                asm volatile("s_waitcnt vmcnt(10) lgkmcnt(0)\n\ts_barrier" ::: "memory");
            else if (s == 14)
                asm volatile("s_waitcnt vmcnt(5) lgkmcnt(0)\n\ts_barrier" ::: "memory");
            else
                asm volatile("s_waitcnt vmcnt(0) lgkmcnt(0)\n\ts_barrier" ::: "memory");
            if (s + 3 < 16) stage((s + 3) & 3, s + 3);
            const int bsel = s & 3;
            const int koq = wk * 4 + q;
            half8 ah[2], al[2], bh[3], bl[3];
            #pragma unroll
            for (int ti = 0; ti < 2; ti++) {
                int r = ms * 32 + ti * 16 + l16;
                ah[ti] = *(const half8*)&lds[bsel][(koq * 64 + r) * 8];
                al[ti] = *(const half8*)&lds[bsel][(512 + koq * 64 + r) * 8];
            }
            #pragma unroll
            for (int tj = 0; tj < 3; tj++) {
                int r = ns * 48 + tj * 16 + l16;
                bh[tj] = *(const half8*)&lds[bsel][(1024 + koq * 96 + r) * 8];
                bl[tj] = *(const half8*)&lds[bsel][(1792 + koq * 96 + r) * 8];
            }
            #pragma unroll
            for (int ti = 0; ti < 2; ti++)
            #pragma unroll
            for (int tj = 0; tj < 3; tj++) {
                int t = ti * 3 + tj;
                acc1[t] = __builtin_amdgcn_mfma_f32_16x16x32_f16(ah[ti], bh[tj], acc1[t], 0, 0, 0);
                acc2[t] = __builtin_amdgcn_mfma_f32_16x16x32_f16(ah[ti], bl[tj], acc2[t], 0, 0, 0);
                acc2[t] = __builtin_amdgcn_mfma_f32_16x16x32_f16(al[ti], bh[tj], acc2[t], 0, 0, 0);
            }
        }
        __syncthreads();
        // cross-wk reduce; scratch aliases LDS buffer 0 (free after k-loop)
        float (*red)[96] = reinterpret_cast<float (*)[96]>(&lds[0][0]);
        if (wk == 1) {
            #pragma unroll
            for (int ti = 0; ti < 2; ti++)
            #pragma unroll
            for (int tj = 0; tj < 3; tj++) {
                f32x4 c = acc1[ti * 3 + tj] + acc2[ti * 3 + tj] * ks;
                #pragma unroll
                for (int rr = 0; rr < 4; rr++)
                    red[ms * 32 + ti * 16 + q * 4 + rr][ns * 48 + tj * 16 + l16] = c[rr];
            }
        }
        __syncthreads();
        if (wk == 0) {
            #pragma unroll
            for (int ti = 0; ti < 2; ti++)
            #pragma unroll
            for (int tj = 0; tj < 3; tj++) {
                f32x4 c = acc1[ti * 3 + tj] + acc2[ti * 3 + tj] * ks;
                #pragma unroll
                for (int rr = 0; rr < 4; rr++) {
                    int row = ms * 32 + ti * 16 + q * 4 + rr;
                    int col = ns * 48 + tj * 16 + l16;
                    red[row][col] += c[rr];
                }
            }
        }
        __syncthreads();
        // GRU gate math + h_new plane emission (operands prefetched)
        {
            float4 sr = *(float4*)&red[erow][ecg];
            float4 sz = *(float4*)&red[erow][32 + ecg];
            float4 sn = *(float4*)&red[erow][64 + ecg];
            ushort4 oh, ol;
#define GRUC(c) { \
            float hp = h2f(hh4.c) + h2f(hl4.c) * ks; \
            float r_ = 1.f / (1.f + expf(-(xr.c + sr.c + br4.c))); \
            float z_ = 1.f / (1.f + expf(-(xz.c + sz.c + bz4.c))); \
            float n_ = tanhf(xn.c + r_ * (sn.c + bn4.c)); \
            float o_ = (1.f - z_) * n_ + z_ * hp; \
            split_h2(o_, oh.c, ol.c); }
            GRUC(x) GRUC(y) GRUC(z) GRUC(w)
#undef GRUC
            *(ushort4*)&dstH[po] = oh;
            *(ushort4*)&dstL[po] = ol;
        }
        if (ttl + 1 < nsteps)
            grid_barrier(bar, tbase + 256u * (unsigned)(ttl + 1));
    }
}

// ---------------------------------------------------------------------------
// C[M,NN] = A @ W^T + bias, from pre-split fp16 planes (row-major [rows][Kp]).
// Used for x-projections and the head GEMMs. (unchanged, verified)
// ---------------------------------------------------------------------------
__global__ __launch_bounds__(256, 2) void gemm_h2(
    const unsigned short* __restrict__ Ah, const unsigned short* __restrict__ Al,
    const unsigned short* __restrict__ Bh, const unsigned short* __restrict__ Bl,
    const float* __restrict__ bias, float* __restrict__ C,
    int M, int NN, int Kp, int nnb)
{
    __shared__ __align__(16) unsigned short lds[2][4][8][64][8]; // 64 KiB

    const int id  = blockIdx.x;
    const int nns = nnb >> 3;
    const int xcd = id & 7;
    const int j   = id >> 3;
    const int bn  = (xcd * nns + j % nns) << 6;
    const int bm  = (j / nns) << 6;

    const int tid  = threadIdx.x;
    const int lane = tid & 63;
    const int wave = tid >> 6;
    const int ws   = wave & 1;
    const int wk   = wave >> 1;
    const int q    = lane >> 4;
    const int l16  = lane & 15;

    const unsigned short* gplane = (wave == 0) ? Ah : (wave == 1) ? Al
                                 : (wave == 2) ? Bh : Bl;
    const unsigned short* gsrc = gplane + (long)(((wave < 2) ? bm : bn) + lane) * Kp;

    f32x4 acc1[2][4] = {};
    f32x4 acc2[2][4] = {};

    const int NS = Kp >> 6;

    #pragma unroll
    for (int jk = 0; jk < 8; jk++)
        g2lds16(gsrc + jk * 8, &lds[0][wave][jk][0][0]);

    int buf = 0;
    for (int s = 0; s < NS; s++) {
        __syncthreads();
        if (s + 1 < NS) {
            const unsigned short* g2 = gsrc + (s + 1) * 64;
            #pragma unroll
            for (int jk = 0; jk < 8; jk++)
                g2lds16(g2 + jk * 8, &lds[buf ^ 1][wave][jk][0][0]);
        }
        const int ko = wk * 4 + q;
        half8 ah[2], al[2], bh[4], bl[4];
        #pragma unroll
        for (int ti = 0; ti < 2; ti++) {
            ah[ti] = *(const half8*)&lds[buf][0][ko][ws * 32 + ti * 16 + l16][0];
            al[ti] = *(const half8*)&lds[buf][1][ko][ws * 32 + ti * 16 + l16][0];
        }
        #pragma unroll
        for (int tj = 0; tj < 4; tj++) {
            bh[tj] = *(const half8*)&lds[buf][2][ko][tj * 16 + l16][0];
            bl[tj] = *(const half8*)&lds[buf][3][ko][tj * 16 + l16][0];
        }
        #pragma unroll
        for (int ti = 0; ti < 2; ti++)
        #pragma unroll
        for (int tj = 0; tj < 4; tj++) {
            acc1[ti][tj] = __builtin_amdgcn_mfma_f32_16x16x32_f16(ah[ti], bh[tj], acc1[ti][tj], 0, 0, 0);
            acc2[ti][tj] = __builtin_amdgcn_mfma_f32_16x16x32_f16(ah[ti], bl[tj], acc2[ti][tj], 0, 0, 0);
            acc2[ti][tj] = __builtin_amdgcn_mfma_f32_16x16x32_f16(al[ti], bh[tj], acc2[ti][tj], 0, 0, 0);
        }
        buf ^= 1;
    }

    __syncthreads();
    float* red = (float*)&lds[0][0][0][0][0];
    const float kscale = 1.0f / 4096.0f;
    if (wk == 1) {
        #pragma unroll
        for (int ti = 0; ti < 2; ti++)
        #pragma unroll
        for (int tj = 0; tj < 4; tj++) {
            f32x4 c = acc1[ti][tj] + acc2[ti][tj] * kscale;
            #pragma unroll
            for (int r = 0; r < 4; r++)
                red[(ws * 32 + ti * 16 + q * 4 + r) * 64 + tj * 16 + l16] = c[r];
        }
    }
    __syncthreads();
    if (wk == 0) {
        #pragma unroll
        for (int ti = 0; ti < 2; ti++)
        #pragma unroll
        for (int tj = 0; tj < 4; tj++) {
            int gn = bn + tj * 16 + l16;
            if (gn < NN) {
                float bv = bias[gn];
                f32x4 c = acc1[ti][tj] + acc2[ti][tj] * kscale;
                #pragma unroll
                for (int r = 0; r < 4; r++) {
                    int row = ws * 32 + ti * 16 + q * 4 + r;
                    C[(long)(bm + row) * NN + gn] = c[r] + red[row * 64 + tj * 16 + l16] + bv;
                }
            }
        }
    }
}

// ---------------------------------------------------------------------------
// generic fp32 matrix -> fp16 plane pair, zero-padded to [Rp][Cp]. (unchanged)
// ---------------------------------------------------------------------------
__global__ __launch_bounds__(256) void split_mat(
    const float* __restrict__ src, long outer_stride, long inner_stride, int inner_shift,
    int R, int C, int cshift,
    unsigned short* __restrict__ ph, unsigned short* __restrict__ pl)
{
    int t = blockIdx.x * 256 + threadIdx.x;
    int row = t >> cshift;
    int c0 = (t & ((1 << cshift) - 1)) << 3;
    float v[8];
    if (row < R) {
        const float* s = src + ((long)(row >> inner_shift)) * outer_stride
                             + ((long)(row & ((1 << inner_shift) - 1))) * inner_stride;
        if (c0 + 8 <= C) {
            float4 a = *(const float4*)(s + c0);
            float4 b = *(const float4*)(s + c0 + 4);
            v[0]=a.x; v[1]=a.y; v[2]=a.z; v[3]=a.w;
            v[4]=b.x; v[5]=b.y; v[6]=b.z; v[7]=b.w;
        } else {
            #pragma unroll
            for (int j2 = 0; j2 < 8; j2++) { int cc = c0 + j2; v[j2] = (cc < C) ? s[cc] : 0.f; }
        }
    } else {
        #pragma unroll
        for (int j2 = 0; j2 < 8; j2++) v[j2] = 0.f;
    }
    unsigned short hh[8], ll[8];
    #pragma unroll
    for (int j2 = 0; j2 < 8; j2++) split_h2(v[j2], hh[j2], ll[j2]);
    long o = ((long)t << 3);
    ushort4 h0 = {hh[0],hh[1],hh[2],hh[3]}, h1 = {hh[4],hh[5],hh[6],hh[7]};
    ushort4 l0 = {ll[0],ll[1],ll[2],ll[3]}, l1 = {ll[4],ll[5],ll[6],ll[7]};
    *(ushort4*)&ph[o] = h0; *(ushort4*)&ph[o + 4] = h1;
    *(ushort4*)&pl[o] = l0; *(ushort4*)&pl[o + 4] = l1;
}

// ---------------------------------------------------------------------------
// block reductions (256 threads = 4 waves of 64)
// ---------------------------------------------------------------------------
__device__ __forceinline__ float block_reduce_sum(float v) {
    __shared__ float red[4];
    #pragma unroll
    for (int o = 32; o > 0; o >>= 1) v += __shfl_down(v, o);
    __syncthreads();
    if ((threadIdx.x & 63) == 0) red[threadIdx.x >> 6] = v;
    __syncthreads();
    return red[0] + red[1] + red[2] + red[3];
}

__device__ __forceinline__ float block_reduce_max(float v) {
    __shared__ float red[4];
    #pragma unroll
    for (int o = 32; o > 0; o >>= 1) v = fmaxf(v, __shfl_down(v, o));
    __syncthreads();
    if ((threadIdx.x & 63) == 0) red[threadIdx.x >> 6] = v;
    __syncthreads();
    return fmaxf(fmaxf(red[0], red[1]), fmaxf(red[2], red[3]));
}

// ---------------------------------------------------------------------------
// LayerNorm + SiLU, in-place on z [B, H]; also emits fp16 planes
// ---------------------------------------------------------------------------
__global__ __launch_bounds__(256) void ln_silu(
    float* __restrict__ z,
    const float* __restrict__ gamma,
    const float* __restrict__ beta,
    unsigned short* __restrict__ ph, unsigned short* __restrict__ pl)
{
    int b = blockIdx.x;
    float* row = z + (long)b * HID;
    float v[4];
    float s = 0.f;
    #pragma unroll
    for (int i = 0; i < 4; i++) { v[i] = row[threadIdx.x + 256 * i]; s += v[i]; }
    float mean = block_reduce_sum(s) * (1.f / HID);
    float vs = 0.f;
    #pragma unroll
    for (int i = 0; i < 4; i++) { float d = v[i] - mean; vs += d * d; }
    float var = block_reduce_sum(vs) * (1.f / HID);
    float inv = 1.f / sqrtf(var + 1e-5f);
    #pragma unroll
    for (int i = 0; i < 4; i++) {
        int col = threadIdx.x + 256 * i;
        float zz = (v[i] - mean) * inv * gamma[col] + beta[col];
        float sv = zz / (1.f + expf(-zz));
        row[col] = sv;
        unsigned short hh, ll;
        split_h2(sv, hh, ll);
        ph[(long)b * HID + col] = hh;
        pl[(long)b * HID + col] = ll;
    }
}

// ---------------------------------------------------------------------------
// mask(<0 -> -inf) + softmax + clip[0,0.1] + 20-iter rebalance; block per row
// ---------------------------------------------------------------------------
__global__ __launch_bounds__(256) void head_softmax_rebalance(
    const float* __restrict__ scores,
    float* __restrict__ out)
{
    int b = blockIdx.x;
    const float* srow = scores + (long)b * NIN;
    int i0 = threadIdx.x;
    int i1 = threadIdx.x + 256;
    bool v1 = (i1 < NIN);

    float s0 = srow[i0];
    if (s0 < 0.f) s0 = -INFINITY;
    float s1 = v1 ? srow[i1] : -INFINITY;
    if (s1 < 0.f) s1 = -INFINITY;

    float m  = block_reduce_max(fmaxf(s0, s1));
    float e0 = expf(s0 - m);
    float e1 = v1 ? expf(s1 - m) : 0.f;
    float Z  = block_reduce_sum(e0 + e1);

    float w0 = fminf(fmaxf(e0 / Z, 0.f), 0.1f);
    float w1 = v1 ? fminf(fmaxf(e1 / Z, 0.f), 0.1f) : 0.f;

    for (int it = 0; it < 20; it++) {
        float total  = block_reduce_sum(w0 + w1);
        float excess = total - 1.f;
        bool active  = excess > 1e-6f;
        float sur0 = fmaxf(w0 - 0.1f, 0.f);
        float sur1 = fmaxf(w1 - 0.1f, 0.f);
        float totsur = block_reduce_sum(sur0 + sur1);
        float u0, u1;
        if (totsur > 0.f) {
            float k = excess / fmaxf(totsur, 1e-12f);
            u0 = w0 - sur0 * k;
            u1 = w1 - sur1 * k;
        } else {
            u0 = w0 - excess / (float)NIN;
            u1 = w1 - excess / (float)NIN;
        }
        u0 = fminf(fmaxf(u0, 0.f), 0.1f);
        u1 = fminf(fmaxf(u1, 0.f), 0.1f);
        if (active) { w0 = u0; w1 = u1; }
    }

    out[(long)b * NIN + i0] = w0;
    if (v1) out[(long)b * NIN + i1] = w1;
}

// ---------------------------------------------------------------------------
extern "C" void kernel_launch(void* const* d_in, const int* in_sizes, int n_in,
                              void* d_out, int out_size, void* d_ws, size_t ws_size,
                              hipStream_t stream)
{
    const float* x     = (const float*)d_in[0];
    const float* w_ih0 = (const float*)d_in[1];
    const float* w_hh0 = (const float*)d_in[2];
    const float* b_ih0 = (const float*)d_in[3];
    const float* b_hh0 = (const float*)d_in[4];
    const float* w_ih1 = (const float*)d_in[5];
    const float* w_hh1 = (const float*)d_in[6];
    const float* b_ih1 = (const float*)d_in[7];
    const float* b_hh1 = (const float*)d_in[8];
    const float* w1    = (const float*)d_in[9];
    const float* b1    = (const float*)d_in[10];
    const float* ln_g  = (const float*)d_in[11];
    const float* ln_b  = (const float*)d_in[12];
    const float* w2    = (const float*)d_in[13];
    const float* b2    = (const float*)d_in[14];
    float* out = (float*)d_out;

    // launch-mode select (host-only queries, capture-safe):
    // 2 = plain persistent launch (grid=256, 160KiB LDS -> 1 block/CU, all
    //     co-resident when ncu>=256);  1 = cooperative;  0 = per-step.
    static int launch_mode = -1;
    if (launch_mode < 0) {
        int dev = 0; hipGetDevice(&dev);
        int ncu = 0;
        hipDeviceGetAttribute(&ncu, hipDeviceAttributeMultiprocessorCount, dev);
        int ca = 0;
        hipDeviceGetAttribute(&ca, hipDeviceAttributeCooperativeLaunch, dev);
        if (ncu >= 256) launch_mode = 2;
        else if (ca)    launch_mode = 1;
        else            launch_mode = 0;
    }

    // ---- workspace carve (64B aligned slots, sizes in floats) ----
    float* wsf = (float*)d_ws;
    auto alloc = [&](size_t nfl) { float* p = wsf; wsf += (nfl + 15) & ~(size_t)15; return p; };

    const size_t BH  = (size_t)BATCH * HID;       // 524288 elems
    const size_t BG  = (size_t)BATCH * G3;

    unsigned* bar = (unsigned*)alloc(16);
    float* zb = alloc(BH);
    float* sc = alloc((size_t)BATCH * NIN);
    unsigned short* pzbh = (unsigned short*)alloc(BH / 2);
    unsigned short* pzbl = (unsigned short*)alloc(BH / 2);
    unsigned short* ph1  = (unsigned short*)alloc(BH);        // 2 slots
    unsigned short* pl1  = (unsigned short*)alloc(BH);
    const size_t W0 = (size_t)G3 * 512;
    const size_t WH = (size_t)G3 * HID;
    const size_t W1s = (size_t)HID * HID;
    const size_t W2s = (size_t)512 * HID;
    unsigned short* pwih0h = (unsigned short*)alloc(W0 / 2);
    unsigned short* pwih0l = (unsigned short*)alloc(W0 / 2);
    unsigned short* pwhh0h = (unsigned short*)alloc(WH / 2);
    unsigned short* pwhh0l = (unsigned short*)alloc(WH / 2);
    unsigned short* pwih1h = (unsigned short*)alloc(WH / 2);
    unsigned short* pwih1l = (unsigned short*)alloc(WH / 2);
    unsigned short* pwhh1h = (unsigned short*)alloc(WH / 2);
    unsigned short* pwhh1l = (unsigned short*)alloc(WH / 2);
    unsigned short* pw1h   = (unsigned short*)alloc(W1s / 2);
    unsigned short* pw1l   = (unsigned short*)alloc(W1s / 2);
    unsigned short* pw2h   = (unsigned short*)alloc(W2s / 2);
    unsigned short* pw2l   = (unsigned short*)alloc(W2s / 2);
    size_t fixed_floats = (size_t)(wsf - (float*)d_ws);

    // per-Tc floats: gxc (Tc*BG) + pxh/pxl + ph0/pl0
    int Tc = 2;
    const int cands[7] = {128, 64, 32, 16, 8, 4, 2};
    for (int ci = 0; ci < 7; ci++) {
        size_t need = fixed_floats + (size_t)cands[ci] * 2359296ULL + 4096;
        if (need * sizeof(float) <= ws_size) { Tc = cands[ci]; break; }
    }
    float* gxc = alloc((size_t)Tc * BG);
    unsigned short* pxh = (unsigned short*)alloc((size_t)Tc * BATCH * 512 / 2);
    unsigned short* pxl = (unsigned short*)alloc((size_t)Tc * BATCH * 512 / 2);
    unsigned short* ph0 = (unsigned short*)alloc((size_t)Tc * BH / 2);
    unsigned short* pl0 = (unsigned short*)alloc((size_t)Tc * BH / 2);

    // zero-init: barrier counter, layer-0 carry-in slot (Tc-1), layer-1 slot 0
    hipMemsetAsync(bar, 0, sizeof(unsigned), stream);
    hipMemsetAsync(ph0 + (size_t)(Tc - 1) * BH, 0, BH * sizeof(unsigned short), stream);
    hipMemsetAsync(pl0 + (size_t)(Tc - 1) * BH, 0, BH * sizeof(unsigned short), stream);
    hipMemsetAsync(ph1, 0, BH * sizeof(unsigned short), stream);
    hipMemsetAsync(pl1, 0, BH * sizeof(unsigned short), stream);

    dim3 blk(256);

    // ---- one-time weight splits ----
    split_mat<<<dim3(G3 * 512 / 2048), blk, 0, stream>>>(w_ih0, 0L, (long)NIN, 30, G3, NIN, 6, pwih0h, pwih0l);
    split_mat<<<dim3(G3 * HID / 2048), blk, 0, stream>>>(w_hh0, 0L, (long)HID, 30, G3, HID, 7, pwhh0h, pwhh0l);
    split_mat<<<dim3(G3 * HID / 2048), blk, 0, stream>>>(w_ih1, 0L, (long)HID, 30, G3, HID, 7, pwih1h, pwih1l);
    split_mat<<<dim3(G3 * HID / 2048), blk, 0, stream>>>(w_hh1, 0L, (long)HID, 30, G3, HID, 7, pwhh1h, pwhh1l);
    split_mat<<<dim3(HID * HID / 2048), blk, 0, stream>>>(w1, 0L, (long)HID, 30, HID, HID, 7, pw1h, pw1l);
    split_mat<<<dim3(512 * HID / 2048), blk, 0, stream>>>(w2, 0L, (long)HID, 30, NIN, HID, 7, pw2h, pw2l);

    unsigned tbase = 0;   // monotonic barrier-target base across persistent launches

    auto launch_gru = [&](unsigned short* pHb, unsigned short* pLb, int nslots, int mode,
                          int tt0, int nsteps,
                          const unsigned short* Whp, const unsigned short* Wlp,
                          const float* bhhp, const float* gxp) {
        if (launch_mode == 2) {
            gru_fused<<<dim3(256), dim3(512), 0, stream>>>(
                pHb, pLb, nslots, mode, tt0, nsteps, Whp, Wlp, bhhp, gxp, bar, tbase);
            tbase += 256u * (unsigned)(nsteps - 1);
        } else if (launch_mode == 1) {
            void* args[] = {&pHb, &pLb, &nslots, &mode, &tt0, &nsteps,
                            (void*)&Whp, (void*)&Wlp, (void*)&bhhp, (void*)&gxp,
                            (void*)&bar, &tbase};
            hipLaunchCooperativeKernel(gru_fused, dim3(256), dim3(512), args, 0, stream);
            tbase += 256u * (unsigned)(nsteps - 1);
        } else {
            for (int tt = 0; tt < nsteps; tt++)
                gru_fused<<<dim3(256), dim3(512), 0, stream>>>(
                    pHb, pLb, nslots, mode, tt0 + tt, 1, Whp, Wlp, bhhp,
                    gxp + (size_t)tt * (512 * 3072), bar, 0u);
        }
    };

    for (int c = 0; c < SEQ_T / Tc; c++) {
        int t0 = c * Tc;
        // x chunk -> fp16 planes [tt*512+b][512]
        split_mat<<<dim3(Tc * BATCH * 512 / 2048), blk, 0, stream>>>(
            x + (long)t0 * NIN, (long)NIN, (long)SEQ_T * NIN, 9,
            Tc * BATCH, NIN, 6, pxh, pxl);
        // layer-0 x-projection for the whole chunk
        gemm_h2<<<dim3((Tc * BATCH / 64) * 48), blk, 0, stream>>>(
            pxh, pxl, pwih0h, pwih0l, b_ih0, gxc, Tc * BATCH, G3, 512, 48);
        // layer-0 recurrence (persistent fused)
        launch_gru(ph0, pl0, Tc, 0, 0, Tc, pwhh0h, pwhh0l, b_hh0, gxc);
        // layer-1 x-projection from h0 planes
        gemm_h2<<<dim3((Tc * BATCH / 64) * 48), blk, 0, stream>>>(
            ph0, pl0, pwih1h, pwih1l, b_ih1, gxc, Tc * BATCH, G3, 1024, 48);
        // layer-1 recurrence (persistent fused)
        launch_gru(ph1, pl1, 2, 1, t0, Tc, pwhh1h, pwhh1l, b_hh1, gxc);
    }
    // final layer-1 h: t=127 writes slot (127&1)^1 = 0 -> ph1 base
    gemm_h2<<<dim3(8 * 16), blk, 0, stream>>>(ph1, pl1, pw1h, pw1l, b1, zb, BATCH, HID, 1024, 16);
    ln_silu<<<dim3(BATCH), blk, 0, stream>>>(zb, ln_g, ln_b, pzbh, pzbl);
    gemm_h2<<<dim3(8 * 8), blk, 0, stream>>>(pzbh, pzbl, pw2h, pw2l, b2, sc, BATCH, NIN, 1024, 8);
    head_softmax_rebalance<<<dim3(BATCH), blk, 0, stream>>>(sc, out);
}

// Round 5
// 12098.725 us; speedup vs baseline: 1.3986x; 1.3986x over previous
//
#include <hip/hip_runtime.h>
#include <math.h>

#define BATCH 512
#define SEQ_T 128
#define NIN   500
#define HID   1024
#define G3    3072   // 3*HID

typedef float f32x4 __attribute__((ext_vector_type(4)));
typedef _Float16 half8 __attribute__((ext_vector_type(8)));

// ---------------------------------------------------------------------------
// fp32 -> fp16 pair split: v ~= h + l/4096, |err| <= ~2^-23 |v|.
// ---------------------------------------------------------------------------
__device__ __forceinline__ void split_h2(float v, unsigned short &h, unsigned short &l) {
    _Float16 hh = (_Float16)v;
    float hf = (float)hh;
    if (fabsf(hf) < 6.103515625e-5f) { hh = (_Float16)0.f; hf = 0.f; }
    _Float16 ll = (_Float16)((v - hf) * 4096.f);
    h = __builtin_bit_cast(unsigned short, hh);
    l = __builtin_bit_cast(unsigned short, ll);
}

__device__ __forceinline__ float h2f(unsigned short u) {
    return (float)__builtin_bit_cast(_Float16, u);
}

__device__ __forceinline__ void g2lds16(const void* g, void* l) {
    __builtin_amdgcn_global_load_lds(
        (const __attribute__((address_space(1))) void*)g,
        (__attribute__((address_space(3))) void*)l,
        16, 0, 0);
}

// ---------------------------------------------------------------------------
// One fused GRU timestep (per-step dispatch; no grid barrier — the stream
// boundary provides cross-XCD coherence and ordering).
// grid = 256 blocks (8 m-tiles x 32 h-tiles), 512 thr (8 waves), 1 block/CU.
// gh = h_prev @ w_hh^T for this block's 32 h-cols x 3 gates (n=96),
// fp16-pair MFMA (chains hh + (hl+lh)/4096); epilogue = GRU gate math +
// h_new fp16-plane emission. K-loop: depth-3 staging pipeline over 4 LDS
// buffers (160 KiB) with counted-vmcnt asm barriers (never vmcnt(0)
// mid-loop). blockIdx->XCD mapping is stable across dispatches, so each
// XCD's W slice stays L2-resident over all 128 steps.
// ---------------------------------------------------------------------------
__global__ __launch_bounds__(512, 1) void gru_step(
    const unsigned short* __restrict__ srcH, const unsigned short* __restrict__ srcL,
    unsigned short* __restrict__ dstH, unsigned short* __restrict__ dstL,
    const unsigned short* __restrict__ Wh, const unsigned short* __restrict__ Wl,
    const float* __restrict__ bhh,
    const float* __restrict__ gxt)
{
    // per-buffer slab layout (16B slots): [0,512) Ah [oct][row64]; [512,1024)
    // Al; [1024,1792) Wh [oct][row96]; [1792,2560) Wl. 40960 B x 4 = 160 KiB.
    // Reduce scratch (64x96 f32 = 24 KiB) aliases buffer 0 after the k-loop.
    __shared__ __align__(16) unsigned short lds[4][2560 * 8];

    const int tid  = threadIdx.x;
    const int lane = tid & 63;
    const int wave = tid >> 6;
    const int ms = wave >> 2, ns = (wave >> 1) & 1, wk = wave & 1;
    const int q = lane >> 4, l16 = lane & 15;
    const int mt = blockIdx.x >> 5, ht = blockIdx.x & 31;  // bid%8 = ht%8 -> stable XCD per ht
    const int bm = mt << 6, hbase = ht << 5;

    // W staging sources (3 chunks/thread)
    const unsigned short* wsrc[3];
    #pragma unroll
    for (int i = 0; i < 3; i++) {
        int u = tid + 512 * i;                 // 0..1535
        int pl = u / 768; int rem = u - pl * 768;
        int oct = rem / 96; int r96 = rem - oct * 96;
        int g = r96 >> 5, wr = r96 & 31;
        wsrc[i] = (pl ? Wl : Wh) + (long)((g << 10) + hbase + wr) * 1024 + oct * 8;
    }

    // epilogue mapping: thread -> (row, 4 h-cols)
    const int erow = tid >> 3;
    const int ecg  = (tid & 7) << 2;
    const float ks = 1.0f / 4096.0f;
    const int grow = bm + erow;
    const long po = (long)grow * 1024 + hbase + ecg;

    // ---- epilogue prefetch: issued first (oldest vmem; drains at s=0) ----
    const float* gp = gxt + (long)grow * 3072 + hbase + ecg;
    float4 xr = *(const float4*)gp;
    float4 xz = *(const float4*)(gp + 1024);
    float4 xn = *(const float4*)(gp + 2048);
    ushort4 hh4 = *(const ushort4*)&srcH[po];
    ushort4 hl4 = *(const ushort4*)&srcL[po];
    const float4 br4 = *(const float4*)&bhh[hbase + ecg];
    const float4 bz4 = *(const float4*)&bhh[1024 + hbase + ecg];
    const float4 bn4 = *(const float4*)&bhh[2048 + hbase + ecg];

    const unsigned short* aH = srcH + (long)(bm + lane) * 1024 + wave * 8;
    const unsigned short* aL = srcL + (long)(bm + lane) * 1024 + wave * 8;

    auto stage = [&](int b, int s) {
        const long ko = (long)s * 64;
        g2lds16(aH + ko,      &lds[b][(0 * 512 + wave * 64) * 8]);
        g2lds16(aL + ko,      &lds[b][(1 * 512 + wave * 64) * 8]);
        g2lds16(wsrc[0] + ko, &lds[b][(2 * 512 + wave * 64) * 8]);
        g2lds16(wsrc[1] + ko, &lds[b][(3 * 512 + wave * 64) * 8]);
        g2lds16(wsrc[2] + ko, &lds[b][(4 * 512 + wave * 64) * 8]);
    };

    f32x4 acc1[6] = {};
    f32x4 acc2[6] = {};
    stage(0, 0);
    stage(1, 1);
    stage(2, 2);
    #pragma unroll
    for (int s = 0; s < 16; s++) {
        // Complete slab s's 5 staging loads (per wave); keep the 10 loads of
        // slabs s+1,s+2 in flight. lgkmcnt(0): prior ds_reads landed -> safe
        // for post-barrier DMA to overwrite buffer (s+3)&3.
        if (s <= 13)
            asm volatile("s_waitcnt vmcnt(10) lgkmcnt(0)\n\ts_barrier" ::: "memory");
        else if (s == 14)
            asm volatile("s_waitcnt vmcnt(5) lgkmcnt(0)\n\ts_barrier" ::: "memory");
        else
            asm volatile("s_waitcnt vmcnt(0) lgkmcnt(0)\n\ts_barrier" ::: "memory");
        if (s + 3 < 16) stage((s + 3) & 3, s + 3);
        const int bsel = s & 3;
        const int koq = wk * 4 + q;
        half8 ah[2], al[2], bh[3], bl[3];
        #pragma unroll
        for (int ti = 0; ti < 2; ti++) {
            int r = ms * 32 + ti * 16 + l16;
            ah[ti] = *(const half8*)&lds[bsel][(koq * 64 + r) * 8];
            al[ti] = *(const half8*)&lds[bsel][(512 + koq * 64 + r) * 8];
        }
        #pragma unroll
        for (int tj = 0; tj < 3; tj++) {
            int r = ns * 48 + tj * 16 + l16;
            bh[tj] = *(const half8*)&lds[bsel][(1024 + koq * 96 + r) * 8];
            bl[tj] = *(const half8*)&lds[bsel][(1792 + koq * 96 + r) * 8];
        }
        #pragma unroll
        for (int ti = 0; ti < 2; ti++)
        #pragma unroll
        for (int tj = 0; tj < 3; tj++) {
            int t = ti * 3 + tj;
            acc1[t] = __builtin_amdgcn_mfma_f32_16x16x32_f16(ah[ti], bh[tj], acc1[t], 0, 0, 0);
            acc2[t] = __builtin_amdgcn_mfma_f32_16x16x32_f16(ah[ti], bl[tj], acc2[t], 0, 0, 0);
            acc2[t] = __builtin_amdgcn_mfma_f32_16x16x32_f16(al[ti], bh[tj], acc2[t], 0, 0, 0);
        }
    }
    __syncthreads();
    // cross-wk reduce; scratch aliases LDS buffer 0 (dead after k-loop)
    float (*red)[96] = reinterpret_cast<float (*)[96]>(&lds[0][0]);
    if (wk == 1) {
        #pragma unroll
        for (int ti = 0; ti < 2; ti++)
        #pragma unroll
        for (int tj = 0; tj < 3; tj++) {
            f32x4 c = acc1[ti * 3 + tj] + acc2[ti * 3 + tj] * ks;
            #pragma unroll
            for (int rr = 0; rr < 4; rr++)
                red[ms * 32 + ti * 16 + q * 4 + rr][ns * 48 + tj * 16 + l16] = c[rr];
        }
    }
    __syncthreads();
    if (wk == 0) {
        #pragma unroll
        for (int ti = 0; ti < 2; ti++)
        #pragma unroll
        for (int tj = 0; tj < 3; tj++) {
            f32x4 c = acc1[ti * 3 + tj] + acc2[ti * 3 + tj] * ks;
            #pragma unroll
            for (int rr = 0; rr < 4; rr++) {
                int row = ms * 32 + ti * 16 + q * 4 + rr;
                int col = ns * 48 + tj * 16 + l16;
                red[row][col] += c[rr];
            }
        }
    }
    __syncthreads();
    // GRU gate math + h_new plane emission (operands prefetched)
    {
        float4 sr = *(float4*)&red[erow][ecg];
        float4 sz = *(float4*)&red[erow][32 + ecg];
        float4 sn = *(float4*)&red[erow][64 + ecg];
        ushort4 oh, ol;
#define GRUC(c) { \
        float hp = h2f(hh4.c) + h2f(hl4.c) * ks; \
        float r_ = 1.f / (1.f + expf(-(xr.c + sr.c + br4.c))); \
        float z_ = 1.f / (1.f + expf(-(xz.c + sz.c + bz4.c))); \
        float n_ = tanhf(xn.c + r_ * (sn.c + bn4.c)); \
        float o_ = (1.f - z_) * n_ + z_ * hp; \
        split_h2(o_, oh.c, ol.c); }
        GRUC(x) GRUC(y) GRUC(z) GRUC(w)
#undef GRUC
        *(ushort4*)&dstH[po] = oh;
        *(ushort4*)&dstL[po] = ol;
    }
}

// ---------------------------------------------------------------------------
// C[M,NN] = A @ W^T + bias, from pre-split fp16 planes (row-major [rows][Kp]).
// Used for x-projections and the head GEMMs. (unchanged, verified)
// ---------------------------------------------------------------------------
__global__ __launch_bounds__(256, 2) void gemm_h2(
    const unsigned short* __restrict__ Ah, const unsigned short* __restrict__ Al,
    const unsigned short* __restrict__ Bh, const unsigned short* __restrict__ Bl,
    const float* __restrict__ bias, float* __restrict__ C,
    int M, int NN, int Kp, int nnb)
{
    __shared__ __align__(16) unsigned short lds[2][4][8][64][8]; // 64 KiB

    const int id  = blockIdx.x;
    const int nns = nnb >> 3;
    const int xcd = id & 7;
    const int j   = id >> 3;
    const int bn  = (xcd * nns + j % nns) << 6;
    const int bm  = (j / nns) << 6;

    const int tid  = threadIdx.x;
    const int lane = tid & 63;
    const int wave = tid >> 6;
    const int ws   = wave & 1;
    const int wk   = wave >> 1;
    const int q    = lane >> 4;
    const int l16  = lane & 15;

    const unsigned short* gplane = (wave == 0) ? Ah : (wave == 1) ? Al
                                 : (wave == 2) ? Bh : Bl;
    const unsigned short* gsrc = gplane + (long)(((wave < 2) ? bm : bn) + lane) * Kp;

    f32x4 acc1[2][4] = {};
    f32x4 acc2[2][4] = {};

    const int NS = Kp >> 6;

    #pragma unroll
    for (int jk = 0; jk < 8; jk++)
        g2lds16(gsrc + jk * 8, &lds[0][wave][jk][0][0]);

    int buf = 0;
    for (int s = 0; s < NS; s++) {
        __syncthreads();
        if (s + 1 < NS) {
            const unsigned short* g2 = gsrc + (s + 1) * 64;
            #pragma unroll
            for (int jk = 0; jk < 8; jk++)
                g2lds16(g2 + jk * 8, &lds[buf ^ 1][wave][jk][0][0]);
        }
        const int ko = wk * 4 + q;
        half8 ah[2], al[2], bh[4], bl[4];
        #pragma unroll
        for (int ti = 0; ti < 2; ti++) {
            ah[ti] = *(const half8*)&lds[buf][0][ko][ws * 32 + ti * 16 + l16][0];
            al[ti] = *(const half8*)&lds[buf][1][ko][ws * 32 + ti * 16 + l16][0];
        }
        #pragma unroll
        for (int tj = 0; tj < 4; tj++) {
            bh[tj] = *(const half8*)&lds[buf][2][ko][tj * 16 + l16][0];
            bl[tj] = *(const half8*)&lds[buf][3][ko][tj * 16 + l16][0];
        }
        #pragma unroll
        for (int ti = 0; ti < 2; ti++)
        #pragma unroll
        for (int tj = 0; tj < 4; tj++) {
            acc1[ti][tj] = __builtin_amdgcn_mfma_f32_16x16x32_f16(ah[ti], bh[tj], acc1[ti][tj], 0, 0, 0);
            acc2[ti][tj] = __builtin_amdgcn_mfma_f32_16x16x32_f16(ah[ti], bl[tj], acc2[ti][tj], 0, 0, 0);
            acc2[ti][tj] = __builtin_amdgcn_mfma_f32_16x16x32_f16(al[ti], bh[tj], acc2[ti][tj], 0, 0, 0);
        }
        buf ^= 1;
    }

    __syncthreads();
    float* red = (float*)&lds[0][0][0][0][0];
    const float kscale = 1.0f / 4096.0f;
    if (wk == 1) {
        #pragma unroll
        for (int ti = 0; ti < 2; ti++)
        #pragma unroll
        for (int tj = 0; tj < 4; tj++) {
            f32x4 c = acc1[ti][tj] + acc2[ti][tj] * kscale;
            #pragma unroll
            for (int r = 0; r < 4; r++)
                red[(ws * 32 + ti * 16 + q * 4 + r) * 64 + tj * 16 + l16] = c[r];
        }
    }
    __syncthreads();
    if (wk == 0) {
        #pragma unroll
        for (int ti = 0; ti < 2; ti++)
        #pragma unroll
        for (int tj = 0; tj < 4; tj++) {
            int gn = bn + tj * 16 + l16;
            if (gn < NN) {
                float bv = bias[gn];
                f32x4 c = acc1[ti][tj] + acc2[ti][tj] * kscale;
                #pragma unroll
                for (int r = 0; r < 4; r++) {
                    int row = ws * 32 + ti * 16 + q * 4 + r;
                    C[(long)(bm + row) * NN + gn] = c[r] + red[row * 64 + tj * 16 + l16] + bv;
                }
            }
        }
    }
}

// ---------------------------------------------------------------------------
// generic fp32 matrix -> fp16 plane pair, zero-padded to [Rp][Cp]. (unchanged)
// ---------------------------------------------------------------------------
__global__ __launch_bounds__(256) void split_mat(
    const float* __restrict__ src, long outer_stride, long inner_stride, int inner_shift,
    int R, int C, int cshift,
    unsigned short* __restrict__ ph, unsigned short* __restrict__ pl)
{
    int t = blockIdx.x * 256 + threadIdx.x;
    int row = t >> cshift;
    int c0 = (t & ((1 << cshift) - 1)) << 3;
    float v[8];
    if (row < R) {
        const float* s = src + ((long)(row >> inner_shift)) * outer_stride
                             + ((long)(row & ((1 << inner_shift) - 1))) * inner_stride;
        if (c0 + 8 <= C) {
            float4 a = *(const float4*)(s + c0);
            float4 b = *(const float4*)(s + c0 + 4);
            v[0]=a.x; v[1]=a.y; v[2]=a.z; v[3]=a.w;
            v[4]=b.x; v[5]=b.y; v[6]=b.z; v[7]=b.w;
        } else {
            #pragma unroll
            for (int j2 = 0; j2 < 8; j2++) { int cc = c0 + j2; v[j2] = (cc < C) ? s[cc] : 0.f; }
        }
    } else {
        #pragma unroll
        for (int j2 = 0; j2 < 8; j2++) v[j2] = 0.f;
    }
    unsigned short hh[8], ll[8];
    #pragma unroll
    for (int j2 = 0; j2 < 8; j2++) split_h2(v[j2], hh[j2], ll[j2]);
    long o = ((long)t << 3);
    ushort4 h0 = {hh[0],hh[1],hh[2],hh[3]}, h1 = {hh[4],hh[5],hh[6],hh[7]};
    ushort4 l0 = {ll[0],ll[1],ll[2],ll[3]}, l1 = {ll[4],ll[5],ll[6],ll[7]};
    *(ushort4*)&ph[o] = h0; *(ushort4*)&ph[o + 4] = h1;
    *(ushort4*)&pl[o] = l0; *(ushort4*)&pl[o + 4] = l1;
}

// ---------------------------------------------------------------------------
// block reductions (256 threads = 4 waves of 64)
// ---------------------------------------------------------------------------
__device__ __forceinline__ float block_reduce_sum(float v) {
    __shared__ float red[4];
    #pragma unroll
    for (int o = 32; o > 0; o >>= 1) v += __shfl_down(v, o);
    __syncthreads();
    if ((threadIdx.x & 63) == 0) red[threadIdx.x >> 6] = v;
    __syncthreads();
    return red[0] + red[1] + red[2] + red[3];
}

__device__ __forceinline__ float block_reduce_max(float v) {
    __shared__ float red[4];
    #pragma unroll
    for (int o = 32; o > 0; o >>= 1) v = fmaxf(v, __shfl_down(v, o));
    __syncthreads();
    if ((threadIdx.x & 63) == 0) red[threadIdx.x >> 6] = v;
    __syncthreads();
    return fmaxf(fmaxf(red[0], red[1]), fmaxf(red[2], red[3]));
}

// ---------------------------------------------------------------------------
// LayerNorm + SiLU, in-place on z [B, H]; also emits fp16 planes
// ---------------------------------------------------------------------------
__global__ __launch_bounds__(256) void ln_silu(
    float* __restrict__ z,
    const float* __restrict__ gamma,
    const float* __restrict__ beta,
    unsigned short* __restrict__ ph, unsigned short* __restrict__ pl)
{
    int b = blockIdx.x;
    float* row = z + (long)b * HID;
    float v[4];
    float s = 0.f;
    #pragma unroll
    for (int i = 0; i < 4; i++) { v[i] = row[threadIdx.x + 256 * i]; s += v[i]; }
    float mean = block_reduce_sum(s) * (1.f / HID);
    float vs = 0.f;
    #pragma unroll
    for (int i = 0; i < 4; i++) { float d = v[i] - mean; vs += d * d; }
    float var = block_reduce_sum(vs) * (1.f / HID);
    float inv = 1.f / sqrtf(var + 1e-5f);
    #pragma unroll
    for (int i = 0; i < 4; i++) {
        int col = threadIdx.x + 256 * i;
        float zz = (v[i] - mean) * inv * gamma[col] + beta[col];
        float sv = zz / (1.f + expf(-zz));
        row[col] = sv;
        unsigned short hh, ll;
        split_h2(sv, hh, ll);
        ph[(long)b * HID + col] = hh;
        pl[(long)b * HID + col] = ll;
    }
}

// ---------------------------------------------------------------------------
// mask(<0 -> -inf) + softmax + clip[0,0.1] + 20-iter rebalance; block per row
// ---------------------------------------------------------------------------
__global__ __launch_bounds__(256) void head_softmax_rebalance(
    const float* __restrict__ scores,
    float* __restrict__ out)
{
    int b = blockIdx.x;
    const float* srow = scores + (long)b * NIN;
    int i0 = threadIdx.x;
    int i1 = threadIdx.x + 256;
    bool v1 = (i1 < NIN);

    float s0 = srow[i0];
    if (s0 < 0.f) s0 = -INFINITY;
    float s1 = v1 ? srow[i1] : -INFINITY;
    if (s1 < 0.f) s1 = -INFINITY;

    float m  = block_reduce_max(fmaxf(s0, s1));
    float e0 = expf(s0 - m);
    float e1 = v1 ? expf(s1 - m) : 0.f;
    float Z  = block_reduce_sum(e0 + e1);

    float w0 = fminf(fmaxf(e0 / Z, 0.f), 0.1f);
    float w1 = v1 ? fminf(fmaxf(e1 / Z, 0.f), 0.1f) : 0.f;

    for (int it = 0; it < 20; it++) {
        float total  = block_reduce_sum(w0 + w1);
        float excess = total - 1.f;
        bool active  = excess > 1e-6f;
        float sur0 = fmaxf(w0 - 0.1f, 0.f);
        float sur1 = fmaxf(w1 - 0.1f, 0.f);
        float totsur = block_reduce_sum(sur0 + sur1);
        float u0, u1;
        if (totsur > 0.f) {
            float k = excess / fmaxf(totsur, 1e-12f);
            u0 = w0 - sur0 * k;
            u1 = w1 - sur1 * k;
        } else {
            u0 = w0 - excess / (float)NIN;
            u1 = w1 - excess / (float)NIN;
        }
        u0 = fminf(fmaxf(u0, 0.f), 0.1f);
        u1 = fminf(fmaxf(u1, 0.f), 0.1f);
        if (active) { w0 = u0; w1 = u1; }
    }

    out[(long)b * NIN + i0] = w0;
    if (v1) out[(long)b * NIN + i1] = w1;
}

// ---------------------------------------------------------------------------
extern "C" void kernel_launch(void* const* d_in, const int* in_sizes, int n_in,
                              void* d_out, int out_size, void* d_ws, size_t ws_size,
                              hipStream_t stream)
{
    const float* x     = (const float*)d_in[0];
    const float* w_ih0 = (const float*)d_in[1];
    const float* w_hh0 = (const float*)d_in[2];
    const float* b_ih0 = (const float*)d_in[3];
    const float* b_hh0 = (const float*)d_in[4];
    const float* w_ih1 = (const float*)d_in[5];
    const float* w_hh1 = (const float*)d_in[6];
    const float* b_ih1 = (const float*)d_in[7];
    const float* b_hh1 = (const float*)d_in[8];
    const float* w1    = (const float*)d_in[9];
    const float* b1    = (const float*)d_in[10];
    const float* ln_g  = (const float*)d_in[11];
    const float* ln_b  = (const float*)d_in[12];
    const float* w2    = (const float*)d_in[13];
    const float* b2    = (const float*)d_in[14];
    float* out = (float*)d_out;

    // ---- workspace carve (64B aligned slots, sizes in floats) ----
    float* wsf = (float*)d_ws;
    auto alloc = [&](size_t nfl) { float* p = wsf; wsf += (nfl + 15) & ~(size_t)15; return p; };

    const size_t BH  = (size_t)BATCH * HID;       // 524288 elems
    const size_t BG  = (size_t)BATCH * G3;

    float* zb = alloc(BH);
    float* sc = alloc((size_t)BATCH * NIN);
    unsigned short* pzbh = (unsigned short*)alloc(BH / 2);
    unsigned short* pzbl = (unsigned short*)alloc(BH / 2);
    unsigned short* ph1  = (unsigned short*)alloc(BH);        // 2 slots
    unsigned short* pl1  = (unsigned short*)alloc(BH);
    const size_t W0 = (size_t)G3 * 512;
    const size_t WH = (size_t)G3 * HID;
    const size_t W1s = (size_t)HID * HID;
    const size_t W2s = (size_t)512 * HID;
    unsigned short* pwih0h = (unsigned short*)alloc(W0 / 2);
    unsigned short* pwih0l = (unsigned short*)alloc(W0 / 2);
    unsigned short* pwhh0h = (unsigned short*)alloc(WH / 2);
    unsigned short* pwhh0l = (unsigned short*)alloc(WH / 2);
    unsigned short* pwih1h = (unsigned short*)alloc(WH / 2);
    unsigned short* pwih1l = (unsigned short*)alloc(WH / 2);
    unsigned short* pwhh1h = (unsigned short*)alloc(WH / 2);
    unsigned short* pwhh1l = (unsigned short*)alloc(WH / 2);
    unsigned short* pw1h   = (unsigned short*)alloc(W1s / 2);
    unsigned short* pw1l   = (unsigned short*)alloc(W1s / 2);
    unsigned short* pw2h   = (unsigned short*)alloc(W2s / 2);
    unsigned short* pw2l   = (unsigned short*)alloc(W2s / 2);
    size_t fixed_floats = (size_t)(wsf - (float*)d_ws);

    // per-Tc floats: gxc (Tc*BG) + pxh/pxl + ph0/pl0
    int Tc = 2;
    const int cands[7] = {128, 64, 32, 16, 8, 4, 2};
    for (int ci = 0; ci < 7; ci++) {
        size_t need = fixed_floats + (size_t)cands[ci] * 2359296ULL + 4096;
        if (need * sizeof(float) <= ws_size) { Tc = cands[ci]; break; }
    }
    float* gxc = alloc((size_t)Tc * BG);
    unsigned short* pxh = (unsigned short*)alloc((size_t)Tc * BATCH * 512 / 2);
    unsigned short* pxl = (unsigned short*)alloc((size_t)Tc * BATCH * 512 / 2);
    unsigned short* ph0 = (unsigned short*)alloc((size_t)Tc * BH / 2);
    unsigned short* pl0 = (unsigned short*)alloc((size_t)Tc * BH / 2);

    // zero-init: layer-0 carry-in slot (Tc-1), layer-1 slot 0
    hipMemsetAsync(ph0 + (size_t)(Tc - 1) * BH, 0, BH * sizeof(unsigned short), stream);
    hipMemsetAsync(pl0 + (size_t)(Tc - 1) * BH, 0, BH * sizeof(unsigned short), stream);
    hipMemsetAsync(ph1, 0, BH * sizeof(unsigned short), stream);
    hipMemsetAsync(pl1, 0, BH * sizeof(unsigned short), stream);

    dim3 blk(256);

    // ---- one-time weight splits ----
    split_mat<<<dim3(G3 * 512 / 2048), blk, 0, stream>>>(w_ih0, 0L, (long)NIN, 30, G3, NIN, 6, pwih0h, pwih0l);
    split_mat<<<dim3(G3 * HID / 2048), blk, 0, stream>>>(w_hh0, 0L, (long)HID, 30, G3, HID, 7, pwhh0h, pwhh0l);
    split_mat<<<dim3(G3 * HID / 2048), blk, 0, stream>>>(w_ih1, 0L, (long)HID, 30, G3, HID, 7, pwih1h, pwih1l);
    split_mat<<<dim3(G3 * HID / 2048), blk, 0, stream>>>(w_hh1, 0L, (long)HID, 30, G3, HID, 7, pwhh1h, pwhh1l);
    split_mat<<<dim3(HID * HID / 2048), blk, 0, stream>>>(w1, 0L, (long)HID, 30, HID, HID, 7, pw1h, pw1l);
    split_mat<<<dim3(512 * HID / 2048), blk, 0, stream>>>(w2, 0L, (long)HID, 30, NIN, HID, 7, pw2h, pw2l);

    const size_t sBG = (size_t)BATCH * G3;

    for (int c = 0; c < SEQ_T / Tc; c++) {
        int t0 = c * Tc;
        // x chunk -> fp16 planes [tt*512+b][512]
        split_mat<<<dim3(Tc * BATCH * 512 / 2048), blk, 0, stream>>>(
            x + (long)t0 * NIN, (long)NIN, (long)SEQ_T * NIN, 9,
            Tc * BATCH, NIN, 6, pxh, pxl);
        // layer-0 x-projection for the whole chunk
        gemm_h2<<<dim3((Tc * BATCH / 64) * 48), blk, 0, stream>>>(
            pxh, pxl, pwih0h, pwih0l, b_ih0, gxc, Tc * BATCH, G3, 512, 48);
        // layer-0 recurrence: one dispatch per step (slot seq; carry in slot Tc-1)
        for (int tt = 0; tt < Tc; tt++) {
            int rs = (tt > 0) ? (tt - 1) : (Tc - 1);
            gru_step<<<dim3(256), dim3(512), 0, stream>>>(
                ph0 + (size_t)rs * BH, pl0 + (size_t)rs * BH,
                ph0 + (size_t)tt * BH, pl0 + (size_t)tt * BH,
                pwhh0h, pwhh0l, b_hh0, gxc + (size_t)tt * sBG);
        }
        // layer-1 x-projection from h0 planes
        gemm_h2<<<dim3((Tc * BATCH / 64) * 48), blk, 0, stream>>>(
            ph0, pl0, pwih1h, pwih1l, b_ih1, gxc, Tc * BATCH, G3, 1024, 48);
        // layer-1 recurrence: ping-pong by global-step parity
        for (int tt = 0; tt < Tc; tt++) {
            int t = t0 + tt;
            int rs = t & 1, wslot = (t & 1) ^ 1;
            gru_step<<<dim3(256), dim3(512), 0, stream>>>(
                ph1 + (size_t)rs * BH, pl1 + (size_t)rs * BH,
                ph1 + (size_t)wslot * BH, pl1 + (size_t)wslot * BH,
                pwhh1h, pwhh1l, b_hh1, gxc + (size_t)tt * sBG);
        }
    }
    // final layer-1 h: t=127 writes slot (127&1)^1 = 0 -> ph1 base
    gemm_h2<<<dim3(8 * 16), blk, 0, stream>>>(ph1, pl1, pw1h, pw1l, b1, zb, BATCH, HID, 1024, 16);
    ln_silu<<<dim3(BATCH), blk, 0, stream>>>(zb, ln_g, ln_b, pzbh, pzbl);
    gemm_h2<<<dim3(8 * 8), blk, 0, stream>>>(pzbh, pzbl, pw2h, pw2l, b2, sc, BATCH, NIN, 1024, 8);
    head_softmax_rebalance<<<dim3(BATCH), blk, 0, stream>>>(sc, out);
}